// Round 3
// baseline (2114.962 us; speedup 1.0000x reference)
//
#include <hip/hip_runtime.h>

#define NN 50000
#define EE 800000
#define TE 32
#define TN 32

typedef unsigned short u16;
typedef unsigned int u32;

__device__ __forceinline__ float siluf(float x) {
    return x / (1.0f + __expf(-x));
}

// 32xK A-tile (LDS f32) @ Kx128 W (global f32, row-major) + bias -> 32x128 out (LDS f32)
// tx=tid&31 -> cols 4tx..4tx+3 ; ty=tid>>5 -> rows 4ty..4ty+3
__device__ __forceinline__ void gemm_tile(
    const float* __restrict__ sA, int strideA, int K,
    const float* __restrict__ W, const float* __restrict__ bias,
    float* __restrict__ sOut, int strideOut, bool doSilu, int tid)
{
    const int tx = tid & 31, ty = tid >> 5;
    const int c = 4 * tx;
    float acc[4][4];
    {
        float4 b = *(const float4*)(bias + c);
        #pragma unroll
        for (int mm = 0; mm < 4; ++mm) {
            acc[mm][0] = b.x; acc[mm][1] = b.y; acc[mm][2] = b.z; acc[mm][3] = b.w;
        }
    }
    const float* aBase = sA + (ty * 4) * strideA;
    for (int k = 0; k < K; ++k) {
        float4 w = *(const float4*)(W + (size_t)k * 128 + c);
        #pragma unroll
        for (int mm = 0; mm < 4; ++mm) {
            float a = aBase[mm * strideA + k];
            acc[mm][0] = fmaf(a, w.x, acc[mm][0]);
            acc[mm][1] = fmaf(a, w.y, acc[mm][1]);
            acc[mm][2] = fmaf(a, w.z, acc[mm][2]);
            acc[mm][3] = fmaf(a, w.w, acc[mm][3]);
        }
    }
    #pragma unroll
    for (int mm = 0; mm < 4; ++mm) {
        int m = ty * 4 + mm;
        #pragma unroll
        for (int j = 0; j < 4; ++j) {
            float v = acc[mm][j];
            if (doSilu) v = siluf(v);
            sOut[m * strideOut + c + j] = v;
        }
    }
}

__global__ __launch_bounds__(256) void edge_kernel(
    const float* __restrict__ h, const float* __restrict__ cdiff,
    const int* __restrict__ row, const int* __restrict__ col,
    const float* __restrict__ We1, const float* __restrict__ be1,
    const float* __restrict__ We2, const float* __restrict__ be2,
    const float* __restrict__ Wc1, const float* __restrict__ bc1,
    const float* __restrict__ Wc2,
    float* __restrict__ agg, float* __restrict__ fsum, float* __restrict__ cnt)
{
    __shared__ float sEin[TE * 260];   // e_in tile [32][257], row stride 260
    __shared__ float sT[TE * 129];     // t1
    __shared__ int sRow[TE];
    __shared__ int sCol[TE];
    __shared__ float sCoef[TE];
    float* sM = sEin;                  // [32][129] m, aliases e_in (dead after layer 1)
    float* sU = sEin + TE * 129;       // [32][129] u  (2*32*129 = 8256 <= 32*260 = 8320)

    const int tid = threadIdx.x;
    const int e0 = blockIdx.x * TE;

    if (tid < TE) {
        int e = e0 + tid;
        sRow[tid] = row[e];
        sCol[tid] = col[e];
        float cx = cdiff[(size_t)e * 3 + 0];
        float cy = cdiff[(size_t)e * 3 + 1];
        float cz = cdiff[(size_t)e * 3 + 2];
        sEin[tid * 260 + 256] = cx * cx + cy * cy + cz * cz;   // radial
    }
    __syncthreads();
    // gather h[row] (cols 0..127) and h[col] (cols 128..255): 32 edges x 64 float4-chunks
    #pragma unroll
    for (int ii = 0; ii < 8; ++ii) {
        int idx = tid + 256 * ii;          // 0..2047
        int e = idx >> 6;
        int c = idx & 63;
        int node = (c < 32) ? sRow[e] : sCol[e];
        int k4 = (c & 31) * 4;
        float4 v = *(const float4*)(h + (size_t)node * 128 + k4);
        *(float4*)(&sEin[e * 260 + ((c < 32) ? k4 : 128 + k4)]) = v;
    }
    __syncthreads();
    // t1 = silu(e_in @ We1 + be1), K=257
    gemm_tile(sEin, 260, 257, We1, be1, sT, 129, true, tid);
    __syncthreads();
    // m = silu(t1 @ We2 + be2)  (writes sM; all sEin reads done at the barrier)
    gemm_tile(sT, 129, 128, We2, be2, sM, 129, true, tid);
    __syncthreads();
    // u = silu(m @ Wc1 + bc1)
    gemm_tile(sM, 129, 128, Wc1, bc1, sU, 129, true, tid);
    __syncthreads();
    // coef = u @ Wc2 (no bias, no silu)
    if (tid < TE) {
        float s = 0.f;
        for (int j = 0; j < 128; ++j) s = fmaf(sU[tid * 129 + j], Wc2[j], s);
        sCoef[tid] = s;
    }
    __syncthreads();
    // force scatter: trans = clip(coord_diff * coef, +-100), segment-sum by row
    if (tid < TE * 3) {
        int e = tid / 3, ax = tid - e * 3;
        float tr = cdiff[(size_t)(e0 + e) * 3 + ax] * sCoef[e];
        tr = fminf(fmaxf(tr, -100.f), 100.f);
        atomicAdd(&fsum[(size_t)sRow[e] * 3 + ax], tr);
    }
    if (tid >= 128 && tid < 128 + TE) {
        atomicAdd(&cnt[sRow[tid - 128]], 1.0f);
    }
    // agg scatter: agg[row[e]] += m[e]
    #pragma unroll
    for (int ii = 0; ii < 16; ++ii) {
        int idx = tid + 256 * ii;          // 0..4095
        int e = idx >> 7, j = idx & 127;
        atomicAdd(&agg[(size_t)sRow[e] * 128 + j], sM[e * 129 + j]);
    }
}

__global__ __launch_bounds__(256) void node_kernel(
    const float* __restrict__ h,
    const float* __restrict__ Wn1, const float* __restrict__ bn1,
    const float* __restrict__ Wn2, const float* __restrict__ bn2,
    const float* __restrict__ Wv1, const float* __restrict__ bv1,
    const float* __restrict__ Wv2, const float* __restrict__ bv2,
    const float* __restrict__ agg, const float* __restrict__ fsum,
    const float* __restrict__ cnt, float* __restrict__ out)
{
    __shared__ float sX[TN * 260];     // [h | agg], 256 cols
    __shared__ float sT2[TN * 129];
    __shared__ float sU2[TN * 129];

    const int tid = threadIdx.x;
    const int n0 = blockIdx.x * TN;

    // stage h -> cols 0..127
    #pragma unroll
    for (int ii = 0; ii < 4; ++ii) {
        int idx = tid + 256 * ii;       // 0..1023
        int r = idx >> 5, c4 = (idx & 31) * 4;
        int n = n0 + r; if (n > NN - 1) n = NN - 1;
        float4 v = *(const float4*)(h + (size_t)n * 128 + c4);
        *(float4*)(&sX[r * 260 + c4]) = v;
    }
    // stage agg (f32) -> cols 128..255
    #pragma unroll
    for (int ii = 0; ii < 4; ++ii) {
        int idx = tid + 256 * ii;       // 0..1023
        int r = idx >> 5, c4 = (idx & 31) * 4;
        int n = n0 + r; if (n > NN - 1) n = NN - 1;
        float4 v = *(const float4*)(agg + (size_t)n * 128 + c4);
        *(float4*)(&sX[r * 260 + 128 + c4]) = v;
    }
    __syncthreads();
    // t = silu([h|agg] @ Wn1 + bn1), K=256
    gemm_tile(sX, 260, 256, Wn1, bn1, sT2, 129, true, tid);
    __syncthreads();
    // h_out = t @ Wn2 + bn2 (no silu)
    gemm_tile(sT2, 129, 128, Wn2, bn2, sU2, 129, false, tid);
    __syncthreads();
    // vel head layer 1: u = silu(h @ Wv1 + bv1) -> sT2 (all sT2 reads done at barrier)
    gemm_tile(sX, 260, 128, Wv1, bv1, sT2, 129, true, tid);
    // store h_out (fp32) — reads sU2, synced by the barrier above
    #pragma unroll
    for (int ii = 0; ii < 4; ++ii) {
        int idx = tid + 256 * ii;        // 0..1023 float4-slots
        int r = idx >> 5, c4 = (idx & 31) * 4;
        int n = n0 + r;
        if (n < NN) {
            float4 v = make_float4(sU2[r * 129 + c4],     sU2[r * 129 + c4 + 1],
                                   sU2[r * 129 + c4 + 2], sU2[r * 129 + c4 + 3]);
            *(float4*)(out + (size_t)4 * NN + (size_t)n * 128 + c4) = v;
        }
    }
    __syncthreads();
    // vel = u @ Wv2 + bv2
    if (tid < TN) {
        int n = n0 + tid;
        if (n < NN) {
            float s = bv2[0];
            for (int j = 0; j < 128; ++j) s = fmaf(sT2[tid * 129 + j], Wv2[j], s);
            out[n] = s;
        }
    }
    // force = f_sum / max(cnt, 1)
    if (tid < TN * 3) {
        int r = tid / 3, ax = tid - r * 3;
        int n = n0 + r;
        if (n < NN) {
            float c = cnt[n];
            float f = fsum[(size_t)n * 3 + ax] / fmaxf(c, 1.0f);
            out[NN + (size_t)n * 3 + ax] = f;
        }
    }
}

extern "C" void kernel_launch(void* const* d_in, const int* in_sizes, int n_in,
                              void* d_out, int out_size, void* d_ws, size_t ws_size,
                              hipStream_t stream) {
    const float* h     = (const float*)d_in[0];
    const float* cdiff = (const float*)d_in[1];
    const int* row     = (const int*)d_in[2];
    const int* col     = (const int*)d_in[3];
    const float* We1 = (const float*)d_in[4];
    const float* be1 = (const float*)d_in[5];
    const float* We2 = (const float*)d_in[6];
    const float* be2 = (const float*)d_in[7];
    const float* Wn1 = (const float*)d_in[8];
    const float* bn1 = (const float*)d_in[9];
    const float* Wn2 = (const float*)d_in[10];
    const float* bn2 = (const float*)d_in[11];
    const float* Wc1 = (const float*)d_in[12];
    const float* bc1 = (const float*)d_in[13];
    const float* Wc2 = (const float*)d_in[14];
    const float* Wv1 = (const float*)d_in[15];
    const float* bv1 = (const float*)d_in[16];
    const float* Wv2 = (const float*)d_in[17];
    const float* bv2 = (const float*)d_in[18];

    float* agg  = (float*)d_ws;                    // [NN*128]
    float* fsum = agg + (size_t)NN * 128;          // [NN*3]
    float* cnt  = fsum + (size_t)NN * 3;           // [NN]
    float* out = (float*)d_out;                    // vel[NN] | force[3*NN] | h_out[128*NN]

    size_t zero_bytes = ((size_t)NN * 128 + (size_t)NN * 3 + (size_t)NN) * sizeof(float);
    hipMemsetAsync(d_ws, 0, zero_bytes, stream);

    edge_kernel<<<EE / TE, 256, 0, stream>>>(h, cdiff, row, col,
                                             We1, be1, We2, be2, Wc1, bc1, Wc2,
                                             agg, fsum, cnt);
    node_kernel<<<(NN + TN - 1) / TN, 256, 0, stream>>>(h, Wn1, bn1, Wn2, bn2,
                                                        Wv1, bv1, Wv2, bv2,
                                                        agg, fsum, cnt, out);
}

// Round 4
// 918.811 us; speedup vs baseline: 2.3018x; 2.3018x over previous
//
#include <hip/hip_runtime.h>

#define NN 50000
#define EE 800000
#define TE 64
#define TN 32

typedef unsigned short u16;
typedef unsigned int u32;
typedef __attribute__((ext_vector_type(8))) short short8;
typedef __attribute__((ext_vector_type(4))) float f32x4;

__device__ __forceinline__ u16 f2bf(float f) {
    union { float f; u32 i; } v; v.f = f;
    u32 x = v.i;
    return (u16)((x + 0x7fffu + ((x >> 16) & 1u)) >> 16);  // RNE
}
__device__ __forceinline__ float bf2f(u16 u) {
    union { u32 i; float f; } v; v.i = ((u32)u) << 16; return v.f;
}
__device__ __forceinline__ u32 pk2(float lo, float hi) {
    return (u32)f2bf(lo) | ((u32)f2bf(hi) << 16);
}
__device__ __forceinline__ float siluf(float x) {
    return x / (1.0f + __expf(-x));
}

// fragment-native layouts: lane-linear 16B chunks per (tile, kchunk)
// A (M=64): a_idx(row,k), row=mt*16+m15, k=c*32+q*8+j
__device__ __forceinline__ int a_idx(int r, int k) {
    return ((k >> 5) << 11) + ((r >> 4) << 9) + (((k >> 3) & 3) << 7) + ((r & 15) << 3) + (k & 7);
}
// B (N=128): b_idx(k,n)
__device__ __forceinline__ int b_idx(int k, int n) {
    return (((k >> 5) << 3) + (n >> 4)) * 512 + (((k >> 3) & 3) << 7) + ((n & 15) << 3) + (k & 7);
}

// ---- prep: fp32 weights -> bf16 fragment-native layout in workspace ----
__global__ __launch_bounds__(256) void prep_kernel(
    const float* __restrict__ We1, const float* __restrict__ We2,
    const float* __restrict__ Wc1,
    u16* __restrict__ We1bf, u16* __restrict__ We2bf, u16* __restrict__ Wc1bf)
{
    int i = blockIdx.x * 256 + threadIdx.x;     // 0..65535
    if (i < 32768) {
        int k = i >> 7, n = i & 127;
        We1bf[b_idx(k, n)] = f2bf(We1[k * 128 + n]);   // rows 0..255 only
    } else if (i < 49152) {
        int t = i - 32768; int k = t >> 7, n = t & 127;
        We2bf[b_idx(k, n)] = f2bf(We2[k * 128 + n]);
    } else {
        int t = i - 49152; int k = t >> 7, n = t & 127;
        Wc1bf[b_idx(k, n)] = f2bf(Wc1[k * 128 + n]);
    }
}

// ---- edge kernel: 64 edges/block, 4 waves, MFMA bf16 ----
__global__ __launch_bounds__(256) void edge_kernel(
    const float* __restrict__ h, const float* __restrict__ cdiff,
    const int* __restrict__ row, const int* __restrict__ col,
    const float* __restrict__ We1, const float* __restrict__ be1,
    const float* __restrict__ be2, const float* __restrict__ bc1,
    const float* __restrict__ Wc2,
    const u16* __restrict__ We1bf, const u16* __restrict__ We2bf,
    const u16* __restrict__ Wc1bf,
    float* __restrict__ agg, float* __restrict__ fsum, float* __restrict__ cnt)
{
    __shared__ u16 sA[16384];      // e_in (A-layout bf16); later reused for u
    __shared__ u16 sT[8192];       // t1
    __shared__ u16 sM[8192];       // m
    __shared__ float sRad[TE];
    __shared__ float sW256[128];
    __shared__ float sB1[128], sB2[128], sB3[128];
    __shared__ int sRow[TE], sCol[TE];
    __shared__ float sCoef[TE];

    const int tid = threadIdx.x;
    const int e0 = blockIdx.x * TE;
    const int w = tid >> 6;
    const int lane = tid & 63;
    const int m15 = lane & 15, q = lane >> 4;

    // stage misc
    if (tid < TE) {
        int e = e0 + tid;
        sRow[tid] = row[e]; sCol[tid] = col[e];
        float cx = cdiff[(size_t)e * 3 + 0];
        float cy = cdiff[(size_t)e * 3 + 1];
        float cz = cdiff[(size_t)e * 3 + 2];
        sRad[tid] = cx * cx + cy * cy + cz * cz;
    } else if (tid < 192) {
        int n = tid - 64;
        sW256[n] = We1[256 * 128 + n];
        sB1[n] = be1[n];
    } else {
        int n = tid - 192;
        sB2[n] = be2[n]; sB2[n + 64] = be2[n + 64];
        sB3[n] = bc1[n]; sB3[n + 64] = bc1[n + 64];
    }
    __syncthreads();

    // gather e_in: thread t -> edge t>>2, 64 k-values
    {
        int e = tid >> 2, p = tid & 3;
        int node = (p < 2) ? sRow[e] : sCol[e];
        const float* src = h + (size_t)node * 128 + (p & 1) * 64;
        int kbase = p * 64;
        #pragma unroll
        for (int g = 0; g < 8; ++g) {
            float4 v0 = *(const float4*)(src + g * 8);
            float4 v1 = *(const float4*)(src + g * 8 + 4);
            uint4 pkd = make_uint4(pk2(v0.x, v0.y), pk2(v0.z, v0.w),
                                   pk2(v1.x, v1.y), pk2(v1.z, v1.w));
            *(uint4*)&sA[a_idx(e, kbase + g * 8)] = pkd;
        }
    }
    __syncthreads();

    f32x4 acc[4][2];

    // ---- GEMM1: t1 = silu(e_in @ We1 + be1), K=256 + radial rank-1 init ----
    #pragma unroll
    for (int ntl = 0; ntl < 2; ++ntl) {
        int colc = (w * 2 + ntl) * 16 + m15;
        float b = sB1[colc], wc = sW256[colc];
        #pragma unroll
        for (int mt = 0; mt < 4; ++mt)
            #pragma unroll
            for (int r = 0; r < 4; ++r)
                acc[mt][ntl][r] = fmaf(sRad[mt * 16 + q * 4 + r], wc, b);
    }
    for (int c = 0; c < 8; ++c) {
        short8 bf0 = *(const short8*)(We1bf + (c * 8 + w * 2 + 0) * 512 + lane * 8);
        short8 bf1 = *(const short8*)(We1bf + (c * 8 + w * 2 + 1) * 512 + lane * 8);
        #pragma unroll
        for (int mt = 0; mt < 4; ++mt) {
            short8 af = *(const short8*)(sA + c * 2048 + mt * 512 + lane * 8);
            acc[mt][0] = __builtin_amdgcn_mfma_f32_16x16x32_bf16(af, bf0, acc[mt][0], 0, 0, 0);
            acc[mt][1] = __builtin_amdgcn_mfma_f32_16x16x32_bf16(af, bf1, acc[mt][1], 0, 0, 0);
        }
    }
    #pragma unroll
    for (int mt = 0; mt < 4; ++mt)
        #pragma unroll
        for (int ntl = 0; ntl < 2; ++ntl) {
            int k = (w * 2 + ntl) * 16 + m15;
            #pragma unroll
            for (int r = 0; r < 4; ++r)
                sT[a_idx(mt * 16 + q * 4 + r, k)] = f2bf(siluf(acc[mt][ntl][r]));
        }
    __syncthreads();

    // ---- GEMM2: m = silu(t1 @ We2 + be2), K=128 ----
    #pragma unroll
    for (int ntl = 0; ntl < 2; ++ntl) {
        float b = sB2[(w * 2 + ntl) * 16 + m15];
        #pragma unroll
        for (int mt = 0; mt < 4; ++mt)
            #pragma unroll
            for (int r = 0; r < 4; ++r)
                acc[mt][ntl][r] = b;
    }
    for (int c = 0; c < 4; ++c) {
        short8 bf0 = *(const short8*)(We2bf + (c * 8 + w * 2 + 0) * 512 + lane * 8);
        short8 bf1 = *(const short8*)(We2bf + (c * 8 + w * 2 + 1) * 512 + lane * 8);
        #pragma unroll
        for (int mt = 0; mt < 4; ++mt) {
            short8 af = *(const short8*)(sT + c * 2048 + mt * 512 + lane * 8);
            acc[mt][0] = __builtin_amdgcn_mfma_f32_16x16x32_bf16(af, bf0, acc[mt][0], 0, 0, 0);
            acc[mt][1] = __builtin_amdgcn_mfma_f32_16x16x32_bf16(af, bf1, acc[mt][1], 0, 0, 0);
        }
    }
    #pragma unroll
    for (int mt = 0; mt < 4; ++mt)
        #pragma unroll
        for (int ntl = 0; ntl < 2; ++ntl) {
            int k = (w * 2 + ntl) * 16 + m15;
            #pragma unroll
            for (int r = 0; r < 4; ++r)
                sM[a_idx(mt * 16 + q * 4 + r, k)] = f2bf(siluf(acc[mt][ntl][r]));
        }
    __syncthreads();

    // ---- GEMM3: u = silu(m @ Wc1 + bc1), K=128 ---- (u -> sA, dead since GEMM1)
    #pragma unroll
    for (int ntl = 0; ntl < 2; ++ntl) {
        float b = sB3[(w * 2 + ntl) * 16 + m15];
        #pragma unroll
        for (int mt = 0; mt < 4; ++mt)
            #pragma unroll
            for (int r = 0; r < 4; ++r)
                acc[mt][ntl][r] = b;
    }
    for (int c = 0; c < 4; ++c) {
        short8 bf0 = *(const short8*)(Wc1bf + (c * 8 + w * 2 + 0) * 512 + lane * 8);
        short8 bf1 = *(const short8*)(Wc1bf + (c * 8 + w * 2 + 1) * 512 + lane * 8);
        #pragma unroll
        for (int mt = 0; mt < 4; ++mt) {
            short8 af = *(const short8*)(sM + c * 2048 + mt * 512 + lane * 8);
            acc[mt][0] = __builtin_amdgcn_mfma_f32_16x16x32_bf16(af, bf0, acc[mt][0], 0, 0, 0);
            acc[mt][1] = __builtin_amdgcn_mfma_f32_16x16x32_bf16(af, bf1, acc[mt][1], 0, 0, 0);
        }
    }
    #pragma unroll
    for (int mt = 0; mt < 4; ++mt)
        #pragma unroll
        for (int ntl = 0; ntl < 2; ++ntl) {
            int k = (w * 2 + ntl) * 16 + m15;
            #pragma unroll
            for (int r = 0; r < 4; ++r)
                sA[a_idx(mt * 16 + q * 4 + r, k)] = f2bf(siluf(acc[mt][ntl][r]));
        }
    __syncthreads();

    // ---- coef = u @ Wc2 ----
    if (tid < TE) {
        float s = 0.f;
        for (int k = 0; k < 128; ++k)
            s = fmaf(bf2f(sA[a_idx(tid, k)]), Wc2[k], s);
        sCoef[tid] = s;
    }
    __syncthreads();

    // force scatter + count
    if (tid < TE * 3) {
        int e = tid / 3, ax = tid - e * 3;
        float tr = cdiff[(size_t)(e0 + e) * 3 + ax] * sCoef[e];
        tr = fminf(fmaxf(tr, -100.f), 100.f);
        atomicAdd(&fsum[(size_t)sRow[e] * 3 + ax], tr);
    } else {
        atomicAdd(&cnt[sRow[tid - 192]], 1.0f);
    }
    // agg scatter: agg[row[e]] += m[e]
    #pragma unroll
    for (int ii = 0; ii < 32; ++ii) {
        int idx = tid + 256 * ii;          // 0..8191
        int e = idx >> 7, j = idx & 127;
        atomicAdd(&agg[(size_t)sRow[e] * 128 + j], bf2f(sM[a_idx(e, j)]));
    }
}

// ---- node kernel (unchanged fp32 VALU) ----
__device__ __forceinline__ void gemm_tile(
    const float* __restrict__ sAp, int strideA, int K,
    const float* __restrict__ W, const float* __restrict__ bias,
    float* __restrict__ sOut, int strideOut, bool doSilu, int tid)
{
    const int tx = tid & 31, ty = tid >> 5;
    const int c = 4 * tx;
    float acc[4][4];
    {
        float4 b = *(const float4*)(bias + c);
        #pragma unroll
        for (int mm = 0; mm < 4; ++mm) {
            acc[mm][0] = b.x; acc[mm][1] = b.y; acc[mm][2] = b.z; acc[mm][3] = b.w;
        }
    }
    const float* aBase = sAp + (ty * 4) * strideA;
    for (int k = 0; k < K; ++k) {
        float4 wv = *(const float4*)(W + (size_t)k * 128 + c);
        #pragma unroll
        for (int mm = 0; mm < 4; ++mm) {
            float a = aBase[mm * strideA + k];
            acc[mm][0] = fmaf(a, wv.x, acc[mm][0]);
            acc[mm][1] = fmaf(a, wv.y, acc[mm][1]);
            acc[mm][2] = fmaf(a, wv.z, acc[mm][2]);
            acc[mm][3] = fmaf(a, wv.w, acc[mm][3]);
        }
    }
    #pragma unroll
    for (int mm = 0; mm < 4; ++mm) {
        int m = ty * 4 + mm;
        #pragma unroll
        for (int j = 0; j < 4; ++j) {
            float v = acc[mm][j];
            if (doSilu) v = siluf(v);
            sOut[m * strideOut + c + j] = v;
        }
    }
}

__global__ __launch_bounds__(256) void node_kernel(
    const float* __restrict__ h,
    const float* __restrict__ Wn1, const float* __restrict__ bn1,
    const float* __restrict__ Wn2, const float* __restrict__ bn2,
    const float* __restrict__ Wv1, const float* __restrict__ bv1,
    const float* __restrict__ Wv2, const float* __restrict__ bv2,
    const float* __restrict__ agg, const float* __restrict__ fsum,
    const float* __restrict__ cnt, float* __restrict__ out)
{
    __shared__ float sX[TN * 260];
    __shared__ float sT2[TN * 129];
    __shared__ float sU2[TN * 129];

    const int tid = threadIdx.x;
    const int n0 = blockIdx.x * TN;

    #pragma unroll
    for (int ii = 0; ii < 4; ++ii) {
        int idx = tid + 256 * ii;
        int r = idx >> 5, c4 = (idx & 31) * 4;
        int n = n0 + r; if (n > NN - 1) n = NN - 1;
        float4 v = *(const float4*)(h + (size_t)n * 128 + c4);
        *(float4*)(&sX[r * 260 + c4]) = v;
    }
    #pragma unroll
    for (int ii = 0; ii < 4; ++ii) {
        int idx = tid + 256 * ii;
        int r = idx >> 5, c4 = (idx & 31) * 4;
        int n = n0 + r; if (n > NN - 1) n = NN - 1;
        float4 v = *(const float4*)(agg + (size_t)n * 128 + c4);
        *(float4*)(&sX[r * 260 + 128 + c4]) = v;
    }
    __syncthreads();
    gemm_tile(sX, 260, 256, Wn1, bn1, sT2, 129, true, tid);
    __syncthreads();
    gemm_tile(sT2, 129, 128, Wn2, bn2, sU2, 129, false, tid);
    __syncthreads();
    gemm_tile(sX, 260, 128, Wv1, bv1, sT2, 129, true, tid);
    #pragma unroll
    for (int ii = 0; ii < 4; ++ii) {
        int idx = tid + 256 * ii;
        int r = idx >> 5, c4 = (idx & 31) * 4;
        int n = n0 + r;
        if (n < NN) {
            float4 v = make_float4(sU2[r * 129 + c4],     sU2[r * 129 + c4 + 1],
                                   sU2[r * 129 + c4 + 2], sU2[r * 129 + c4 + 3]);
            *(float4*)(out + (size_t)4 * NN + (size_t)n * 128 + c4) = v;
        }
    }
    __syncthreads();
    if (tid < TN) {
        int n = n0 + tid;
        if (n < NN) {
            float s = bv2[0];
            for (int j = 0; j < 128; ++j) s = fmaf(sT2[tid * 129 + j], Wv2[j], s);
            out[n] = s;
        }
    }
    if (tid < TN * 3) {
        int r = tid / 3, ax = tid - r * 3;
        int n = n0 + r;
        if (n < NN) {
            float c = cnt[n];
            out[NN + (size_t)n * 3 + ax] = fsum[(size_t)n * 3 + ax] / fmaxf(c, 1.0f);
        }
    }
}

extern "C" void kernel_launch(void* const* d_in, const int* in_sizes, int n_in,
                              void* d_out, int out_size, void* d_ws, size_t ws_size,
                              hipStream_t stream) {
    const float* h     = (const float*)d_in[0];
    const float* cdiff = (const float*)d_in[1];
    const int* row     = (const int*)d_in[2];
    const int* col     = (const int*)d_in[3];
    const float* We1 = (const float*)d_in[4];
    const float* be1 = (const float*)d_in[5];
    const float* We2 = (const float*)d_in[6];
    const float* be2 = (const float*)d_in[7];
    const float* Wn1 = (const float*)d_in[8];
    const float* bn1 = (const float*)d_in[9];
    const float* Wn2 = (const float*)d_in[10];
    const float* bn2 = (const float*)d_in[11];
    const float* Wc1 = (const float*)d_in[12];
    const float* bc1 = (const float*)d_in[13];
    const float* Wc2 = (const float*)d_in[14];
    const float* Wv1 = (const float*)d_in[15];
    const float* bv1 = (const float*)d_in[16];
    const float* Wv2 = (const float*)d_in[17];
    const float* bv2 = (const float*)d_in[18];

    float* agg  = (float*)d_ws;                     // [NN*128]
    float* fsum = agg + (size_t)NN * 128;           // [NN*3]
    float* cnt  = fsum + (size_t)NN * 3;            // [NN]
    u16* We1bf = (u16*)(cnt + NN);                  // [32768]
    u16* We2bf = We1bf + 32768;                     // [16384]
    u16* Wc1bf = We2bf + 16384;                     // [16384]
    float* out = (float*)d_out;

    size_t zero_bytes = ((size_t)NN * 128 + (size_t)NN * 3 + (size_t)NN) * sizeof(float);
    hipMemsetAsync(d_ws, 0, zero_bytes, stream);

    prep_kernel<<<256, 256, 0, stream>>>(We1, We2, Wc1, We1bf, We2bf, Wc1bf);
    edge_kernel<<<EE / TE, 256, 0, stream>>>(h, cdiff, row, col,
                                             We1, be1, be2, bc1, Wc2,
                                             We1bf, We2bf, Wc1bf,
                                             agg, fsum, cnt);
    node_kernel<<<(NN + TN - 1) / TN, 256, 0, stream>>>(h, Wn1, bn1, Wn2, bn2,
                                                        Wv1, bv1, Wv2, bv2,
                                                        agg, fsum, cnt, out);
}

// Round 5
// 592.627 us; speedup vs baseline: 3.5688x; 1.5504x over previous
//
#include <hip/hip_runtime.h>

#define NN 50000
#define EE 800000

typedef unsigned short u16;
typedef unsigned int u32;
typedef __attribute__((ext_vector_type(8))) short short8;
typedef __attribute__((ext_vector_type(4))) float f32x4;

__device__ __forceinline__ u16 f2bf(float f) {
    union { float f; u32 i; } v; v.f = f;
    u32 x = v.i;
    return (u16)((x + 0x7fffu + ((x >> 16) & 1u)) >> 16);  // RNE
}
__device__ __forceinline__ float bf2f(u16 u) {
    union { u32 i; float f; } v; v.i = ((u32)u) << 16; return v.f;
}
__device__ __forceinline__ u32 pk2(float lo, float hi) {
    return (u32)f2bf(lo) | ((u32)f2bf(hi) << 16);
}
__device__ __forceinline__ float siluf(float x) {
    return x / (1.0f + __expf(-x));
}

// fragment-native layouts: lane-linear 16B chunks per (tile, kchunk)
// A (M=64): a_idx(row,k), lane l in chunk holds row=l&15, k=(l>>4)*8+j
__device__ __forceinline__ int a_idx(int r, int k) {
    return ((k >> 5) << 11) + ((r >> 4) << 9) + (((k >> 3) & 3) << 7) + ((r & 15) << 3) + (k & 7);
}
// B (N=128): b_idx(k,n), chunk id = (k>>5)*8 + (n>>4)
__device__ __forceinline__ int b_idx(int k, int n) {
    return (((k >> 5) << 3) + (n >> 4)) * 512 + (((k >> 3) & 3) << 7) + ((n & 15) << 3) + (k & 7);
}

// ---- prep: fp32 weights -> bf16 fragment-native layout in workspace ----
__global__ __launch_bounds__(256) void prep_kernel(
    const float* __restrict__ We1, const float* __restrict__ We2,
    const float* __restrict__ Wc1, const float* __restrict__ Wn1,
    const float* __restrict__ Wn2, const float* __restrict__ Wv1,
    u16* __restrict__ We1bf, u16* __restrict__ We2bf, u16* __restrict__ Wc1bf,
    u16* __restrict__ Wn1bf, u16* __restrict__ Wn2bf, u16* __restrict__ Wv1bf)
{
    int i = blockIdx.x * 256 + threadIdx.x;     // 0..131071
    if (i < 32768) {
        int k = i >> 7, n = i & 127;
        We1bf[b_idx(k, n)] = f2bf(We1[k * 128 + n]);   // rows 0..255
    } else if (i < 49152) {
        int t = i - 32768; int k = t >> 7, n = t & 127;
        We2bf[b_idx(k, n)] = f2bf(We2[k * 128 + n]);
    } else if (i < 65536) {
        int t = i - 49152; int k = t >> 7, n = t & 127;
        Wc1bf[b_idx(k, n)] = f2bf(Wc1[k * 128 + n]);
    } else if (i < 98304) {
        int t = i - 65536; int k = t >> 7, n = t & 127;
        Wn1bf[b_idx(k, n)] = f2bf(Wn1[k * 128 + n]);   // rows 0..255
    } else if (i < 114688) {
        int t = i - 98304; int k = t >> 7, n = t & 127;
        Wn2bf[b_idx(k, n)] = f2bf(Wn2[k * 128 + n]);
    } else {
        int t = i - 114688; int k = t >> 7, n = t & 127;
        Wv1bf[b_idx(k, n)] = f2bf(Wv1[k * 128 + n]);
    }
}

// ---- edge kernel: 64 edges/block, 4 waves, MFMA bf16, ~51KB LDS (3 blocks/CU) ----
__global__ __launch_bounds__(256) void edge_kernel(
    const float* __restrict__ h, const float* __restrict__ cdiff,
    const int* __restrict__ row, const int* __restrict__ col,
    const float* __restrict__ We1, const float* __restrict__ be1,
    const float* __restrict__ be2, const float* __restrict__ bc1,
    const float* __restrict__ Wc2,
    const u16* __restrict__ We1bf, const u16* __restrict__ We2bf,
    const u16* __restrict__ Wc1bf,
    float* __restrict__ agg, float* __restrict__ fsum, float* __restrict__ cnt)
{
    __shared__ u16 sA[16384];      // e_in (A-layout). Upper half reused for m, lower for u.
    __shared__ u16 sT[8192];       // t1
    __shared__ float sRad[64];
    __shared__ float sW256[128];
    __shared__ float sB1[128], sB2[128], sB3[128];
    __shared__ int sRow[64], sCol[64];
    __shared__ float sCoef[64];
    u16* sM = sA + 8192;           // m (A-layout, K=128): e_in k>=128 region, dead after GEMM1
    u16* sU = sA;                  // u (A-layout, K=128): e_in k<128 region, dead after GEMM1

    const int tid = threadIdx.x;
    const int e0 = blockIdx.x * 64;
    const int w = tid >> 6;
    const int lane = tid & 63;
    const int m15 = lane & 15, q = lane >> 4;

    // stage misc
    if (tid < 64) {
        int e = e0 + tid;
        sRow[tid] = row[e]; sCol[tid] = col[e];
        float cx = cdiff[(size_t)e * 3 + 0];
        float cy = cdiff[(size_t)e * 3 + 1];
        float cz = cdiff[(size_t)e * 3 + 2];
        sRad[tid] = cx * cx + cy * cy + cz * cz;
    } else if (tid < 192) {
        int n = tid - 64;
        sW256[n] = We1[256 * 128 + n];
        sB1[n] = be1[n];
    } else {
        int n = tid - 192;
        sB2[n] = be2[n]; sB2[n + 64] = be2[n + 64];
        sB3[n] = bc1[n]; sB3[n + 64] = bc1[n + 64];
    }
    __syncthreads();

    // gather e_in: thread t -> edge t>>2, 64 k-values (bf16-pack to A-layout)
    {
        int e = tid >> 2, p = tid & 3;
        int node = (p < 2) ? sRow[e] : sCol[e];
        const float* src = h + (size_t)node * 128 + (p & 1) * 64;
        int kbase = p * 64;
        #pragma unroll
        for (int g = 0; g < 8; ++g) {
            float4 v0 = *(const float4*)(src + g * 8);
            float4 v1 = *(const float4*)(src + g * 8 + 4);
            uint4 pkd = make_uint4(pk2(v0.x, v0.y), pk2(v0.z, v0.w),
                                   pk2(v1.x, v1.y), pk2(v1.z, v1.w));
            *(uint4*)&sA[a_idx(e, kbase + g * 8)] = pkd;
        }
    }
    if (tid < 64) atomicAdd(&cnt[sRow[tid]], 1.0f);   // fire early
    __syncthreads();

    f32x4 acc[4][2];

    // ---- GEMM1: t1 = silu(e_in @ We1 + be1), K=256 + radial rank-1 init ----
    #pragma unroll
    for (int ntl = 0; ntl < 2; ++ntl) {
        int colc = (w * 2 + ntl) * 16 + m15;
        float b = sB1[colc], wc = sW256[colc];
        #pragma unroll
        for (int mt = 0; mt < 4; ++mt)
            #pragma unroll
            for (int r = 0; r < 4; ++r)
                acc[mt][ntl][r] = fmaf(sRad[mt * 16 + q * 4 + r], wc, b);
    }
    for (int c = 0; c < 8; ++c) {
        short8 bf0 = *(const short8*)(We1bf + (c * 8 + w * 2 + 0) * 512 + lane * 8);
        short8 bf1 = *(const short8*)(We1bf + (c * 8 + w * 2 + 1) * 512 + lane * 8);
        #pragma unroll
        for (int mt = 0; mt < 4; ++mt) {
            short8 af = *(const short8*)(sA + c * 2048 + mt * 512 + lane * 8);
            acc[mt][0] = __builtin_amdgcn_mfma_f32_16x16x32_bf16(af, bf0, acc[mt][0], 0, 0, 0);
            acc[mt][1] = __builtin_amdgcn_mfma_f32_16x16x32_bf16(af, bf1, acc[mt][1], 0, 0, 0);
        }
    }
    #pragma unroll
    for (int mt = 0; mt < 4; ++mt)
        #pragma unroll
        for (int ntl = 0; ntl < 2; ++ntl) {
            int k = (w * 2 + ntl) * 16 + m15;
            #pragma unroll
            for (int r = 0; r < 4; ++r)
                sT[a_idx(mt * 16 + q * 4 + r, k)] = f2bf(siluf(acc[mt][ntl][r]));
        }
    __syncthreads();   // sT ready; sA fully dead -> sM/sU may be written

    // ---- GEMM2: m = silu(t1 @ We2 + be2), K=128; epilogue scatters agg from regs ----
    #pragma unroll
    for (int ntl = 0; ntl < 2; ++ntl) {
        float b = sB2[(w * 2 + ntl) * 16 + m15];
        #pragma unroll
        for (int mt = 0; mt < 4; ++mt)
            #pragma unroll
            for (int r = 0; r < 4; ++r)
                acc[mt][ntl][r] = b;
    }
    for (int c = 0; c < 4; ++c) {
        short8 bf0 = *(const short8*)(We2bf + (c * 8 + w * 2 + 0) * 512 + lane * 8);
        short8 bf1 = *(const short8*)(We2bf + (c * 8 + w * 2 + 1) * 512 + lane * 8);
        #pragma unroll
        for (int mt = 0; mt < 4; ++mt) {
            short8 af = *(const short8*)(sT + c * 2048 + mt * 512 + lane * 8);
            acc[mt][0] = __builtin_amdgcn_mfma_f32_16x16x32_bf16(af, bf0, acc[mt][0], 0, 0, 0);
            acc[mt][1] = __builtin_amdgcn_mfma_f32_16x16x32_bf16(af, bf1, acc[mt][1], 0, 0, 0);
        }
    }
    #pragma unroll
    for (int mt = 0; mt < 4; ++mt)
        #pragma unroll
        for (int ntl = 0; ntl < 2; ++ntl) {
            int k = (w * 2 + ntl) * 16 + m15;
            #pragma unroll
            for (int r = 0; r < 4; ++r) {
                int rw = mt * 16 + q * 4 + r;
                float sm = siluf(acc[mt][ntl][r]);
                sM[a_idx(rw, k)] = f2bf(sm);
                atomicAdd(&agg[(size_t)sRow[rw] * 128 + k], sm);   // coalesced 16-lane runs
            }
        }
    __syncthreads();   // sM ready

    // ---- GEMM3: u = silu(m @ Wc1 + bc1), K=128 -> sU ----
    #pragma unroll
    for (int ntl = 0; ntl < 2; ++ntl) {
        float b = sB3[(w * 2 + ntl) * 16 + m15];
        #pragma unroll
        for (int mt = 0; mt < 4; ++mt)
            #pragma unroll
            for (int r = 0; r < 4; ++r)
                acc[mt][ntl][r] = b;
    }
    for (int c = 0; c < 4; ++c) {
        short8 bf0 = *(const short8*)(Wc1bf + (c * 8 + w * 2 + 0) * 512 + lane * 8);
        short8 bf1 = *(const short8*)(Wc1bf + (c * 8 + w * 2 + 1) * 512 + lane * 8);
        #pragma unroll
        for (int mt = 0; mt < 4; ++mt) {
            short8 af = *(const short8*)(sM + c * 2048 + mt * 512 + lane * 8);
            acc[mt][0] = __builtin_amdgcn_mfma_f32_16x16x32_bf16(af, bf0, acc[mt][0], 0, 0, 0);
            acc[mt][1] = __builtin_amdgcn_mfma_f32_16x16x32_bf16(af, bf1, acc[mt][1], 0, 0, 0);
        }
    }
    #pragma unroll
    for (int mt = 0; mt < 4; ++mt)
        #pragma unroll
        for (int ntl = 0; ntl < 2; ++ntl) {
            int k = (w * 2 + ntl) * 16 + m15;
            #pragma unroll
            for (int r = 0; r < 4; ++r)
                sU[a_idx(mt * 16 + q * 4 + r, k)] = f2bf(siluf(acc[mt][ntl][r]));
        }
    __syncthreads();

    // ---- coef = u @ Wc2 ----
    if (tid < 64) {
        float s = 0.f;
        for (int k = 0; k < 128; ++k)
            s = fmaf(bf2f(sU[a_idx(tid, k)]), Wc2[k], s);
        sCoef[tid] = s;
    }
    __syncthreads();

    // force scatter
    if (tid < 192) {
        int e = tid / 3, ax = tid - e * 3;
        float tr = cdiff[(size_t)(e0 + e) * 3 + ax] * sCoef[e];
        tr = fminf(fmaxf(tr, -100.f), 100.f);
        atomicAdd(&fsum[(size_t)sRow[e] * 3 + ax], tr);
    }
}

// ---- node kernel: 64 nodes/block, 4 waves, MFMA bf16 ----
__global__ __launch_bounds__(256) void node_kernel(
    const float* __restrict__ h,
    const float* __restrict__ bn1, const float* __restrict__ bn2,
    const float* __restrict__ bv1, const float* __restrict__ Wv2,
    const float* __restrict__ bv2,
    const u16* __restrict__ Wn1bf, const u16* __restrict__ Wn2bf,
    const u16* __restrict__ Wv1bf,
    const float* __restrict__ agg, const float* __restrict__ fsum,
    const float* __restrict__ cnt, float* __restrict__ out)
{
    __shared__ u16 sX[16384];      // [h|agg] A-layout K=256; upper half reused for v
    __shared__ u16 sT[8192];
    __shared__ float sBn1[128], sBn2[128], sBv1[128];
    u16* sV = sX + 8192;           // v = silu(h@Wv1+bv1), A-layout K=128

    const int tid = threadIdx.x;
    const int n0 = blockIdx.x * 64;
    const int w = tid >> 6;
    const int lane = tid & 63;
    const int m15 = lane & 15, q = lane >> 4;

    // force = f_sum / max(cnt,1): no LDS dependency, fire first
    if (tid < 192) {
        int r = tid / 3, ax = tid - r * 3;
        int n = n0 + r;
        if (n < NN)
            out[NN + (size_t)n * 3 + ax] = fsum[(size_t)n * 3 + ax] / fmaxf(cnt[n], 1.0f);
    }
    if (tid < 128) { sBn1[tid] = bn1[tid]; sBn2[tid] = bn2[tid]; sBv1[tid] = bv1[tid]; }

    // gather X = [h | agg]: thread t -> node row t>>2
    {
        int e = tid >> 2, p = tid & 3;
        int n = n0 + e; if (n > NN - 1) n = NN - 1;
        const float* src = ((p < 2) ? h : agg) + (size_t)n * 128 + (p & 1) * 64;
        int kbase = p * 64;
        #pragma unroll
        for (int g = 0; g < 8; ++g) {
            float4 v0 = *(const float4*)(src + g * 8);
            float4 v1 = *(const float4*)(src + g * 8 + 4);
            uint4 pkd = make_uint4(pk2(v0.x, v0.y), pk2(v0.z, v0.w),
                                   pk2(v1.x, v1.y), pk2(v1.z, v1.w));
            *(uint4*)&sX[a_idx(e, kbase + g * 8)] = pkd;
        }
    }
    __syncthreads();

    f32x4 acc[4][2];

    // ---- GEMM1: t = silu(X @ Wn1 + bn1), K=256 ----
    #pragma unroll
    for (int ntl = 0; ntl < 2; ++ntl) {
        float b = sBn1[(w * 2 + ntl) * 16 + m15];
        #pragma unroll
        for (int mt = 0; mt < 4; ++mt)
            #pragma unroll
            for (int r = 0; r < 4; ++r)
                acc[mt][ntl][r] = b;
    }
    for (int c = 0; c < 8; ++c) {
        short8 bf0 = *(const short8*)(Wn1bf + (c * 8 + w * 2 + 0) * 512 + lane * 8);
        short8 bf1 = *(const short8*)(Wn1bf + (c * 8 + w * 2 + 1) * 512 + lane * 8);
        #pragma unroll
        for (int mt = 0; mt < 4; ++mt) {
            short8 af = *(const short8*)(sX + c * 2048 + mt * 512 + lane * 8);
            acc[mt][0] = __builtin_amdgcn_mfma_f32_16x16x32_bf16(af, bf0, acc[mt][0], 0, 0, 0);
            acc[mt][1] = __builtin_amdgcn_mfma_f32_16x16x32_bf16(af, bf1, acc[mt][1], 0, 0, 0);
        }
    }
    #pragma unroll
    for (int mt = 0; mt < 4; ++mt)
        #pragma unroll
        for (int ntl = 0; ntl < 2; ++ntl) {
            int k = (w * 2 + ntl) * 16 + m15;
            #pragma unroll
            for (int r = 0; r < 4; ++r)
                sT[a_idx(mt * 16 + q * 4 + r, k)] = f2bf(siluf(acc[mt][ntl][r]));
        }
    __syncthreads();   // sT ready; sX upper dead -> sV writable

    // ---- GEMM2: h_out = t @ Wn2 + bn2 (no silu), direct global store ----
    #pragma unroll
    for (int ntl = 0; ntl < 2; ++ntl) {
        float b = sBn2[(w * 2 + ntl) * 16 + m15];
        #pragma unroll
        for (int mt = 0; mt < 4; ++mt)
            #pragma unroll
            for (int r = 0; r < 4; ++r)
                acc[mt][ntl][r] = b;
    }
    for (int c = 0; c < 4; ++c) {
        short8 bf0 = *(const short8*)(Wn2bf + (c * 8 + w * 2 + 0) * 512 + lane * 8);
        short8 bf1 = *(const short8*)(Wn2bf + (c * 8 + w * 2 + 1) * 512 + lane * 8);
        #pragma unroll
        for (int mt = 0; mt < 4; ++mt) {
            short8 af = *(const short8*)(sT + c * 2048 + mt * 512 + lane * 8);
            acc[mt][0] = __builtin_amdgcn_mfma_f32_16x16x32_bf16(af, bf0, acc[mt][0], 0, 0, 0);
            acc[mt][1] = __builtin_amdgcn_mfma_f32_16x16x32_bf16(af, bf1, acc[mt][1], 0, 0, 0);
        }
    }
    #pragma unroll
    for (int mt = 0; mt < 4; ++mt)
        #pragma unroll
        for (int ntl = 0; ntl < 2; ++ntl) {
            int cl = (w * 2 + ntl) * 16 + m15;
            #pragma unroll
            for (int r = 0; r < 4; ++r) {
                int n = n0 + mt * 16 + q * 4 + r;
                if (n < NN) out[(size_t)4 * NN + (size_t)n * 128 + cl] = acc[mt][ntl][r];
            }
        }

    // ---- GEMM3: v = silu(h @ Wv1 + bv1), K=128 (sX chunks c0..3) -> sV ----
    #pragma unroll
    for (int ntl = 0; ntl < 2; ++ntl) {
        float b = sBv1[(w * 2 + ntl) * 16 + m15];
        #pragma unroll
        for (int mt = 0; mt < 4; ++mt)
            #pragma unroll
            for (int r = 0; r < 4; ++r)
                acc[mt][ntl][r] = b;
    }
    for (int c = 0; c < 4; ++c) {
        short8 bf0 = *(const short8*)(Wv1bf + (c * 8 + w * 2 + 0) * 512 + lane * 8);
        short8 bf1 = *(const short8*)(Wv1bf + (c * 8 + w * 2 + 1) * 512 + lane * 8);
        #pragma unroll
        for (int mt = 0; mt < 4; ++mt) {
            short8 af = *(const short8*)(sX + c * 2048 + mt * 512 + lane * 8);
            acc[mt][0] = __builtin_amdgcn_mfma_f32_16x16x32_bf16(af, bf0, acc[mt][0], 0, 0, 0);
            acc[mt][1] = __builtin_amdgcn_mfma_f32_16x16x32_bf16(af, bf1, acc[mt][1], 0, 0, 0);
        }
    }
    #pragma unroll
    for (int mt = 0; mt < 4; ++mt)
        #pragma unroll
        for (int ntl = 0; ntl < 2; ++ntl) {
            int k = (w * 2 + ntl) * 16 + m15;
            #pragma unroll
            for (int r = 0; r < 4; ++r)
                sV[a_idx(mt * 16 + q * 4 + r, k)] = f2bf(siluf(acc[mt][ntl][r]));
        }
    __syncthreads();

    // vel = v @ Wv2 + bv2
    if (tid < 64) {
        int n = n0 + tid;
        if (n < NN) {
            float s = bv2[0];
            for (int k = 0; k < 128; ++k)
                s = fmaf(bf2f(sV[a_idx(tid, k)]), Wv2[k], s);
            out[n] = s;
        }
    }
}

extern "C" void kernel_launch(void* const* d_in, const int* in_sizes, int n_in,
                              void* d_out, int out_size, void* d_ws, size_t ws_size,
                              hipStream_t stream) {
    const float* h     = (const float*)d_in[0];
    const float* cdiff = (const float*)d_in[1];
    const int* row     = (const int*)d_in[2];
    const int* col     = (const int*)d_in[3];
    const float* We1 = (const float*)d_in[4];
    const float* be1 = (const float*)d_in[5];
    const float* We2 = (const float*)d_in[6];
    const float* be2 = (const float*)d_in[7];
    const float* Wn1 = (const float*)d_in[8];
    const float* bn1 = (const float*)d_in[9];
    const float* Wn2 = (const float*)d_in[10];
    const float* bn2 = (const float*)d_in[11];
    const float* Wc1 = (const float*)d_in[12];
    const float* bc1 = (const float*)d_in[13];
    const float* Wc2 = (const float*)d_in[14];
    const float* Wv1 = (const float*)d_in[15];
    const float* bv1 = (const float*)d_in[16];
    const float* Wv2 = (const float*)d_in[17];
    const float* bv2 = (const float*)d_in[18];

    float* agg  = (float*)d_ws;                     // [NN*128]
    float* fsum = agg + (size_t)NN * 128;           // [NN*3]
    float* cnt  = fsum + (size_t)NN * 3;            // [NN]
    u16* We1bf = (u16*)(cnt + NN);                  // [32768]
    u16* We2bf = We1bf + 32768;                     // [16384]
    u16* Wc1bf = We2bf + 16384;                     // [16384]
    u16* Wn1bf = Wc1bf + 16384;                     // [32768]
    u16* Wn2bf = Wn1bf + 32768;                     // [16384]
    u16* Wv1bf = Wn2bf + 16384;                     // [16384]
    float* out = (float*)d_out;

    size_t zero_bytes = ((size_t)NN * 128 + (size_t)NN * 3 + (size_t)NN) * sizeof(float);
    hipMemsetAsync(d_ws, 0, zero_bytes, stream);

    prep_kernel<<<512, 256, 0, stream>>>(We1, We2, Wc1, Wn1, Wn2, Wv1,
                                         We1bf, We2bf, Wc1bf, Wn1bf, Wn2bf, Wv1bf);
    edge_kernel<<<EE / 64, 256, 0, stream>>>(h, cdiff, row, col,
                                             We1, be1, be2, bc1, Wc2,
                                             We1bf, We2bf, Wc1bf,
                                             agg, fsum, cnt);
    node_kernel<<<(NN + 63) / 64, 256, 0, stream>>>(h, bn1, bn2, bv1, Wv2, bv2,
                                                    Wn1bf, Wn2bf, Wv1bf,
                                                    agg, fsum, cnt, out);
}